// Round 6
// baseline (1711.632 us; speedup 1.0000x reference)
//
#include <hip/hip_runtime.h>
#include <hip/hip_bf16.h>
#include <math.h>

#define NN 10000
#define NE 60000
#define DD 128
#define NL 15
#define LN_EPS 1e-5f

typedef __attribute__((ext_vector_type(8))) short short8;       // 8 bf16 (MFMA A/B frag)
typedef __attribute__((ext_vector_type(4))) float floatx4;      // MFMA C/D frag

__device__ __forceinline__ unsigned short f2bf(float f) {
    unsigned u = __float_as_uint(f);
    u += 0x7fff + ((u >> 16) & 1);   // RNE
    return (unsigned short)(u >> 16);
}
// packed f32x2 -> bf16x2 (v_cvt_pk_bf16_f32 on gfx950), result as one uint
__device__ __forceinline__ unsigned bc2(float a, float b) {
    __hip_bfloat162 t = __float22bfloat162_rn(make_float2(a, b));
    return *(unsigned*)&t;
}
// gelu(y) ~= y * sigmoid(1.5957691*y + 0.0713548*y^3)
__device__ __forceinline__ float gelu_fast(float y) {
    float u = y * y;
    float s2 = y * fmaf(u, 0.07135481283f, 1.59576912161f);
    return y * __builtin_amdgcn_rcpf(1.0f + __expf(-s2));
}

// ---- pack fp32 weights [L][K][N] -> bf16 MFMA B-fragment layout ----
// dst (within layer) = (t*S + s)*512 + l*8 + j ; virtual k = 32s+8(l>>4)+j ; n=16t+(l&15)
// PERM (stage-2 weights, K=256): physical k = ((kv&15)<<4)|(kv>>4)
__device__ __forceinline__ void pack_one(const float* __restrict__ W, unsigned short* __restrict__ P,
                                         int u, int Kk, int Nk, bool perm) {
    int per_layer = Kk * Nk;
    int i = u / per_layer;
    int v0 = u - i * per_layer;
    int S = Kk >> 5;
    int t = v0 / (S * 512);
    int rem = v0 - t * (S * 512);
    int s = rem >> 9;
    int v = rem & 511;
    int l = v >> 3, j = v & 7;
    int kv = (s << 5) + ((l >> 4) << 3) + j;
    int k = perm ? (((kv & 15) << 4) | (kv >> 4)) : kv;
    int n = (t << 4) + (l & 15);
    P[u] = f2bf(W[((size_t)i * Kk + k) * Nk + n]);
}

#define N_EW1 (NL * 384 * 256)
#define N_EW2 (NL * 256 * 128)
#define N_NW1 (NL * 256 * 256)
#define N_NW2 (NL * 256 * 128)

__global__ void pack_all(const float* __restrict__ ew1, const float* __restrict__ ew2,
                         const float* __restrict__ nw1, const float* __restrict__ nw2,
                         unsigned short* __restrict__ P) {
    int tid = blockIdx.x * blockDim.x + threadIdx.x;
    if (tid < N_EW1) { pack_one(ew1, P, tid, 384, 256, false); return; }
    tid -= N_EW1;
    if (tid < N_EW2) { pack_one(ew2, P + N_EW1, tid, 256, 128, true); return; }
    tid -= N_EW2;
    if (tid < N_NW1) { pack_one(nw1, P + N_EW1 + N_EW2, tid, 256, 256, false); return; }
    tid -= N_NW1;
    if (tid < N_NW2) { pack_one(nw2, P + N_EW1 + N_EW2 + N_NW1, tid, 256, 128, true); return; }
}

// ---- CSR build (once per launch) ----
__global__ void hist_kernel(const int* __restrict__ ecol, int* __restrict__ cnt) {
    int e = blockIdx.x * blockDim.x + threadIdx.x;
    if (e < NE) atomicAdd(&cnt[ecol[e]], 1);
}

__global__ void scan_kernel(const int* __restrict__ cnt, int* __restrict__ starts,
                            int* __restrict__ cursor, float* __restrict__ cinv) {
    __shared__ int part[256];
    int t = threadIdx.x;
    const int chunk = (NN + 255) / 256;
    int lo = t * chunk;
    int hi = lo + chunk; if (hi > NN) hi = NN;
    int s = 0;
    for (int n = lo; n < hi; ++n) s += cnt[n];
    part[t] = s;
    __syncthreads();
    for (int off = 1; off < 256; off <<= 1) {
        int v = (t >= off) ? part[t - off] : 0;
        __syncthreads();
        part[t] += v;
        __syncthreads();
    }
    int base = part[t] - s;
    for (int n = lo; n < hi; ++n) {
        int c = cnt[n];
        starts[n] = base; cursor[n] = base;
        cinv[n] = 1.0f / (float)(c > 0 ? c : 1);
        base += c;
    }
}

__global__ void fill_kernel(const int* __restrict__ ecol, int* __restrict__ cursor,
                            int* __restrict__ eidx) {
    int e = blockIdx.x * blockDim.x + threadIdx.x;
    if (e < NE) {
        int slot = atomicAdd(&cursor[ecol[e]], 1);
        eidx[slot] = e;
    }
}

// ---- aggregation: one wave per node, lane covers 2 cols (coalesced 512B/edge) ----
__global__ __launch_bounds__(256)
void agg_kernel(const float* __restrict__ ea, const int* __restrict__ starts,
                const int* __restrict__ cnt, const float* __restrict__ cinv,
                const int* __restrict__ eidx, float* __restrict__ agg) {
    int n = blockIdx.x * 4 + (threadIdx.x >> 6);
    if (n >= NN) return;
    int lane = threadIdx.x & 63;
    int st = starts[n], de = cnt[n];
    float sx = 0.f, sy = 0.f;
    for (int i = 0; i < de; ++i) {
        int e = eidx[st + i];
        const float2 v = *(const float2*)&ea[(size_t)e * DD + lane * 2];
        sx += v.x; sy += v.y;
    }
    float ci = cinv[n];
    float2 o; o.x = sx * ci; o.y = sy * ci;
    *(float2*)&agg[(size_t)n * DD + lane * 2] = o;
}

// ---- fused MFMA MLP: 64 rows/block, 4 waves ----
// stage1: [64,K1]@[K1,256]+b1 -> LN (in-reg + red1) -> GELU -> H' bf16 LDS (b64 writes)
// stage2: wave w owns m-tile w (16 rows, all 128 cols) -> LN2 pure shfl -> target += out
template <int K1, int ROWS_TOTAL, bool EDGE>
__global__ __launch_bounds__(256, 4)
void mlp_mfma(const float* __restrict__ xin,
              const int* __restrict__ erow, const int* __restrict__ ecol,
              const float* __restrict__ aux,        // NODE: agg (dense fp32)
              float* __restrict__ target,           // EDGE: ea ; NODE: x
              const unsigned short* __restrict__ W1p, const unsigned short* __restrict__ W2p,
              const float* __restrict__ b1, const float* __restrict__ g1, const float* __restrict__ bt1,
              const float* __restrict__ b2, const float* __restrict__ g2, const float* __restrict__ bt2)
{
    constexpr int S1 = K1 / 32;
    constexpr int ROWS = 64;
    constexpr int NIT = K1 / 32;      // gather iterations per thread (12 edge, 8 node)
    __shared__ union {
        unsigned short a1[ROWS * K1];     // gather tile (bf16, XOR-swizzled groups of 8)
        unsigned short h[ROWS * 256];     // stage-1 activations, nibble-swapped col layout
    } sm;
    __shared__ float red1[ROWS][8];

    const int tid  = threadIdx.x;
    const int lane = tid & 63;
    const int w    = tid >> 6;
    const int q    = lane >> 4;
    const int c15  = lane & 15;
    const int r0   = blockIdx.x * ROWS;

    // ---------------- gather -> a1: thread owns row r=tid>>2, col-group g=tid&3 ----------------
    {
        const int r = tid >> 2;
        const int g = tid & 3;
        const int row_g = r0 + r;
        const bool ok = (ROWS_TOTAL % ROWS == 0) || (row_g < ROWS_TOTAL);
        const int rg = ok ? row_g : 0;   // clamp: garbage rows never stored (per-row GEMM/LN independence)
        const float* baseA;
        const float* baseB;
        const float* baseC = nullptr;
        if (EDGE) {
            baseA = &xin[(size_t)erow[rg] * DD];
            baseB = &xin[(size_t)ecol[rg] * DD];
            baseC = &target[(size_t)rg * DD];
        } else {
            baseA = &xin[(size_t)rg * DD];
            baseB = &aux[(size_t)rg * DD];
        }
        #pragma unroll
        for (int it = 0; it < NIT; ++it) {
            const int pg = g + (it << 2);      // col-group 0..K1/8-1, region uniform per it
            const int p  = pg << 3;
            const float* src;
            if (p < 128)      src = baseA + p;
            else if (p < 256) src = baseB + (p - 128);
            else              src = baseC + (p - 256);
            float4 v0 = *(const float4*)src;
            float4 v1 = *(const float4*)(src + 4);
            int addr = r * K1 + ((pg ^ (r & 7)) << 3);
            uint4 pk;
            pk.x = bc2(v0.x, v0.y); pk.y = bc2(v0.z, v0.w);
            pk.z = bc2(v1.x, v1.y); pk.w = bc2(v1.z, v1.w);
            *(uint4*)&sm.a1[addr] = pk;
        }
    }
    __syncthreads();

    // ---------------- stage 1 MFMA: wave w -> n-tiles 4w..4w+3, m-tiles 0..3 ----------------
    floatx4 acc[4][4];
    #pragma unroll
    for (int mt = 0; mt < 4; ++mt)
        #pragma unroll
        for (int ntl = 0; ntl < 4; ++ntl)
            acc[mt][ntl] = (floatx4){0.f, 0.f, 0.f, 0.f};

    #pragma unroll
    for (int s = 0; s < S1; ++s) {
        short8 af[4];
        #pragma unroll
        for (int mt = 0; mt < 4; ++mt) {
            int row  = (mt << 4) + c15;
            int kgrp = ((s << 2) + q) ^ (row & 7);
            af[mt] = *(const short8*)&sm.a1[row * K1 + (kgrp << 3)];
        }
        #pragma unroll
        for (int ntl = 0; ntl < 4; ++ntl) {
            const short8 bf = *(const short8*)&W1p[((((((w << 2) + ntl) * S1) + s) << 6) + lane) << 3];
            #pragma unroll
            for (int mt = 0; mt < 4; ++mt)
                acc[mt][ntl] = __builtin_amdgcn_mfma_f32_16x16x32_bf16(af[mt], bf, acc[mt][ntl], 0, 0, 0);
        }
    }

    // bias + in-register LN1 partial stats
    float b1c[4], g1c[4], t1c[4];
    #pragma unroll
    for (int ntl = 0; ntl < 4; ++ntl) {
        int col = (((w << 2) + ntl) << 4) + c15;
        b1c[ntl] = b1[col]; g1c[ntl] = g1[col]; t1c[ntl] = bt1[col];
    }
    #pragma unroll
    for (int mt = 0; mt < 4; ++mt)
        #pragma unroll
        for (int r = 0; r < 4; ++r) {
            float p = 0.f, sq = 0.f;
            #pragma unroll
            for (int ntl = 0; ntl < 4; ++ntl) {
                float v = acc[mt][ntl][r] + b1c[ntl];
                acc[mt][ntl][r] = v;
                p += v; sq += v * v;
            }
            p += __shfl_xor(p, 1);  sq += __shfl_xor(sq, 1);
            p += __shfl_xor(p, 2);  sq += __shfl_xor(sq, 2);
            p += __shfl_xor(p, 4);  sq += __shfl_xor(sq, 4);
            p += __shfl_xor(p, 8);  sq += __shfl_xor(sq, 8);
            if (c15 == 0) {
                int row = (mt << 4) + (q << 2) + r;
                red1[row][(w << 1) + 0] = p;
                red1[row][(w << 1) + 1] = sq;
            }
        }
    __syncthreads();   // red1 visible; all waves done with a1 -> h writes safe

    // ---- apply LN1 + GELU in reg, write H' once as b64 (nibble-swapped cols) ----
    // orig col = (4w+ntl)*16 + c15  ->  col' = c15*16 + 4w + ntl (ntl contiguous)
    #pragma unroll
    for (int mt = 0; mt < 4; ++mt)
        #pragma unroll
        for (int r = 0; r < 4; ++r) {
            int row = (mt << 4) + (q << 2) + r;
            const float4 p0 = *(const float4*)&red1[row][0];
            const float4 p1 = *(const float4*)&red1[row][4];
            float p  = p0.x + p0.z + p1.x + p1.z;
            float sq = p0.y + p0.w + p1.y + p1.w;
            float mu = p * (1.0f / 256.0f);
            float rs = rsqrtf(sq * (1.0f / 256.0f) - mu * mu + LN_EPS);
            float y0 = gelu_fast((acc[mt][0][r] - mu) * rs * g1c[0] + t1c[0]);
            float y1 = gelu_fast((acc[mt][1][r] - mu) * rs * g1c[1] + t1c[1]);
            float y2 = gelu_fast((acc[mt][2][r] - mu) * rs * g1c[2] + t1c[2]);
            float y3 = gelu_fast((acc[mt][3][r] - mu) * rs * g1c[3] + t1c[3]);
            uint2 hp;
            hp.x = bc2(y0, y1);
            hp.y = bc2(y2, y3);
            int gg = (c15 << 1) + (w >> 1);
            int addr = row * 256 + (((gg ^ (row & 7)) << 3) | ((w & 1) << 2));
            *(uint2*)&sm.h[addr] = hp;
        }
    __syncthreads();

    // ---------------- stage 2: wave w owns m-tile w (16 rows), all 8 n-tiles ----------------
    floatx4 acc2[8];
    #pragma unroll
    for (int j = 0; j < 8; ++j) acc2[j] = (floatx4){0.f, 0.f, 0.f, 0.f};

    const int mrow = (w << 4) + c15;
    #pragma unroll
    for (int s = 0; s < 8; ++s) {
        int kgrp = ((s << 2) + q) ^ (mrow & 7);
        const short8 a = *(const short8*)&sm.h[mrow * 256 + (kgrp << 3)];
        #pragma unroll
        for (int j = 0; j < 8; ++j) {
            const short8 b = *(const short8*)&W2p[((((j << 3) + s) << 6) + lane) << 3];
            acc2[j] = __builtin_amdgcn_mfma_f32_16x16x32_bf16(a, b, acc2[j], 0, 0, 0);
        }
    }

    // ---------------- epilogue: bias + LN2 (pure shfl, full row in-wave) + residual store ----
    float b2c[8], g2c[8], t2c[8];
    #pragma unroll
    for (int j = 0; j < 8; ++j) {
        int col = (j << 4) + c15;
        b2c[j] = b2[col]; g2c[j] = g2[col]; t2c[j] = bt2[col];
    }
    #pragma unroll
    for (int r = 0; r < 4; ++r) {
        float p = 0.f, sq = 0.f;
        #pragma unroll
        for (int j = 0; j < 8; ++j) {
            float v = acc2[j][r] + b2c[j];
            acc2[j][r] = v;
            p += v; sq += v * v;
        }
        p += __shfl_xor(p, 1);  sq += __shfl_xor(sq, 1);
        p += __shfl_xor(p, 2);  sq += __shfl_xor(sq, 2);
        p += __shfl_xor(p, 4);  sq += __shfl_xor(sq, 4);
        p += __shfl_xor(p, 8);  sq += __shfl_xor(sq, 8);
        float mu = p * (1.0f / 128.0f);
        float rs = rsqrtf(sq * (1.0f / 128.0f) - mu * mu + LN_EPS);
        int row  = (w << 4) + (q << 2) + r;
        int rowg = r0 + row;
        if (ROWS_TOTAL % ROWS == 0 || rowg < ROWS_TOTAL) {
            #pragma unroll
            for (int j = 0; j < 8; ++j) {
                int col = (j << 4) + c15;
                float o = (acc2[j][r] - mu) * rs * g2c[j] + t2c[j];
                target[(size_t)rowg * DD + col] += o;
            }
        }
    }
}

extern "C" void kernel_launch(void* const* d_in, const int* in_sizes, int n_in,
                              void* d_out, int out_size, void* d_ws, size_t ws_size,
                              hipStream_t stream) {
    const float* x_in  = (const float*)d_in[0];
    const int*   ei    = (const int*)  d_in[1];
    const float* ea_in = (const float*)d_in[2];
    const float* ew1 = (const float*)d_in[3];
    const float* eb1 = (const float*)d_in[4];
    const float* eg1 = (const float*)d_in[5];
    const float* ebt1= (const float*)d_in[6];
    const float* ew2 = (const float*)d_in[7];
    const float* eb2 = (const float*)d_in[8];
    const float* eg2 = (const float*)d_in[9];
    const float* ebt2= (const float*)d_in[10];
    const float* nw1 = (const float*)d_in[11];
    const float* nb1 = (const float*)d_in[12];
    const float* ng1 = (const float*)d_in[13];
    const float* nbt1= (const float*)d_in[14];
    const float* nw2 = (const float*)d_in[15];
    const float* nb2 = (const float*)d_in[16];
    const float* ng2 = (const float*)d_in[17];
    const float* nbt2= (const float*)d_in[18];

    const int* erow = ei;
    const int* ecol = ei + NE;

    float* xbuf  = (float*)d_out;            // [NN, DD]
    float* eabuf = (float*)d_out + NN * DD;  // [NE, DD]

    // workspace layout
    unsigned short* ew1p = (unsigned short*)d_ws;
    unsigned short* ew2p = ew1p + N_EW1;
    unsigned short* nw1p = ew2p + N_EW2;
    unsigned short* nw2p = nw1p + N_NW1;
    int*   cnt    = (int*)(nw2p + N_NW2);
    int*   starts = cnt + NN;
    int*   cursor = starts + NN;
    int*   eidx   = cursor + NN;
    float* cinv   = (float*)(eidx + NE);
    float* agg    = cinv + NN;               // [NN, DD]

    hipMemcpyAsync(xbuf,  x_in,  (size_t)NN * DD * sizeof(float), hipMemcpyDeviceToDevice, stream);
    hipMemcpyAsync(eabuf, ea_in, (size_t)NE * DD * sizeof(float), hipMemcpyDeviceToDevice, stream);

    // CSR build
    hipMemsetAsync(cnt, 0, NN * sizeof(int), stream);
    hist_kernel<<<(NE + 255) / 256, 256, 0, stream>>>(ecol, cnt);
    scan_kernel<<<1, 256, 0, stream>>>(cnt, starts, cursor, cinv);
    fill_kernel<<<(NE + 255) / 256, 256, 0, stream>>>(ecol, cursor, eidx);

    // weight packing (stage-2 weights get the k-permutation)
    {
        int ntot = N_EW1 + N_EW2 + N_NW1 + N_NW2;
        pack_all<<<(ntot + 255) / 256, 256, 0, stream>>>(ew1, ew2, nw1, nw2, ew1p);
    }

    for (int i = 0; i < NL; ++i) {
        mlp_mfma<384, NE, true><<<(NE + 63) / 64, 256, 0, stream>>>(
            xbuf, erow, ecol, nullptr, eabuf,
            ew1p + (size_t)i * 384 * 256, ew2p + (size_t)i * 256 * 128,
            eb1 + (size_t)i * 256, eg1 + (size_t)i * 256, ebt1 + (size_t)i * 256,
            eb2 + (size_t)i * 128, eg2 + (size_t)i * 128, ebt2 + (size_t)i * 128);
        agg_kernel<<<(NN + 3) / 4, 256, 0, stream>>>(eabuf, starts, cnt, cinv, eidx, agg);
        mlp_mfma<256, NN, false><<<(NN + 63) / 64, 256, 0, stream>>>(
            xbuf, nullptr, nullptr, agg, xbuf,
            nw1p + (size_t)i * 256 * 256, nw2p + (size_t)i * 256 * 128,
            nb1 + (size_t)i * 256, ng1 + (size_t)i * 256, nbt1 + (size_t)i * 256,
            nb2 + (size_t)i * 128, ng2 + (size_t)i * 128, nbt2 + (size_t)i * 128);
    }
}

// Round 7
// 1703.955 us; speedup vs baseline: 1.0045x; 1.0045x over previous
//
#include <hip/hip_runtime.h>
#include <hip/hip_bf16.h>
#include <math.h>

#define NN 10000
#define NE 60000
#define DD 128
#define NL 15
#define LN_EPS 1e-5f

typedef __attribute__((ext_vector_type(8))) short short8;       // 8 bf16 (MFMA A/B frag)
typedef __attribute__((ext_vector_type(4))) float floatx4;      // MFMA C/D frag

__device__ __forceinline__ unsigned short f2bf(float f) {
    unsigned u = __float_as_uint(f);
    u += 0x7fff + ((u >> 16) & 1);   // RNE
    return (unsigned short)(u >> 16);
}
// packed f32x2 -> bf16x2 (v_cvt_pk_bf16_f32 on gfx950), result as one uint
__device__ __forceinline__ unsigned bc2(float a, float b) {
    __hip_bfloat162 t = __float22bfloat162_rn(make_float2(a, b));
    return *(unsigned*)&t;
}
// gelu(y) ~= y * sigmoid(1.5957691*y + 0.0713548*y^3)
__device__ __forceinline__ float gelu_fast(float y) {
    float u = y * y;
    float s2 = y * fmaf(u, 0.07135481283f, 1.59576912161f);
    return y * __builtin_amdgcn_rcpf(1.0f + __expf(-s2));
}

// ---- pack fp32 weights [L][K][N] -> bf16 MFMA B-fragment layout ----
// dst (within layer) = (t*S + s)*512 + l*8 + j ; virtual k = 32s+8(l>>4)+j ; n=16t+(l&15)
// PERM (stage-2 weights, K=256): physical k = ((kv&15)<<4)|(kv>>4)
__device__ __forceinline__ void pack_one(const float* __restrict__ W, unsigned short* __restrict__ P,
                                         int u, int Kk, int Nk, bool perm) {
    int per_layer = Kk * Nk;
    int i = u / per_layer;
    int v0 = u - i * per_layer;
    int S = Kk >> 5;
    int t = v0 / (S * 512);
    int rem = v0 - t * (S * 512);
    int s = rem >> 9;
    int v = rem & 511;
    int l = v >> 3, j = v & 7;
    int kv = (s << 5) + ((l >> 4) << 3) + j;
    int k = perm ? (((kv & 15) << 4) | (kv >> 4)) : kv;
    int n = (t << 4) + (l & 15);
    P[u] = f2bf(W[((size_t)i * Kk + k) * Nk + n]);
}

#define N_EW1 (NL * 384 * 256)
#define N_EW2 (NL * 256 * 128)
#define N_NW1 (NL * 256 * 256)
#define N_NW2 (NL * 256 * 128)

__global__ void pack_all(const float* __restrict__ ew1, const float* __restrict__ ew2,
                         const float* __restrict__ nw1, const float* __restrict__ nw2,
                         unsigned short* __restrict__ P) {
    int tid = blockIdx.x * blockDim.x + threadIdx.x;
    if (tid < N_EW1) { pack_one(ew1, P, tid, 384, 256, false); return; }
    tid -= N_EW1;
    if (tid < N_EW2) { pack_one(ew2, P + N_EW1, tid, 256, 128, true); return; }
    tid -= N_EW2;
    if (tid < N_NW1) { pack_one(nw1, P + N_EW1 + N_EW2, tid, 256, 256, false); return; }
    tid -= N_NW1;
    if (tid < N_NW2) { pack_one(nw2, P + N_EW1 + N_EW2 + N_NW1, tid, 256, 128, true); return; }
}

// ---- init bf16 shadows of x and ea ----
__global__ void cvt_shadow(const float* __restrict__ xf, const float* __restrict__ eaf,
                           unsigned short* __restrict__ xb, unsigned short* __restrict__ eab) {
    int i = blockIdx.x * blockDim.x + threadIdx.x;
    const int NX = NN * DD / 4;
    const int NEA = NE * DD / 4;
    if (i < NX) {
        float4 v = ((const float4*)xf)[i];
        uint2 p; p.x = bc2(v.x, v.y); p.y = bc2(v.z, v.w);
        ((uint2*)xb)[i] = p;
    } else if (i < NX + NEA) {
        int j = i - NX;
        float4 v = ((const float4*)eaf)[j];
        uint2 p; p.x = bc2(v.x, v.y); p.y = bc2(v.z, v.w);
        ((uint2*)eab)[j] = p;
    }
}

// ---- CSR build (once per launch) ----
__global__ void hist_kernel(const int* __restrict__ ecol, int* __restrict__ cnt) {
    int e = blockIdx.x * blockDim.x + threadIdx.x;
    if (e < NE) atomicAdd(&cnt[ecol[e]], 1);
}

__global__ void scan_kernel(const int* __restrict__ cnt, int* __restrict__ starts,
                            int* __restrict__ cursor, float* __restrict__ cinv) {
    __shared__ int part[256];
    int t = threadIdx.x;
    const int chunk = (NN + 255) / 256;
    int lo = t * chunk;
    int hi = lo + chunk; if (hi > NN) hi = NN;
    int s = 0;
    for (int n = lo; n < hi; ++n) s += cnt[n];
    part[t] = s;
    __syncthreads();
    for (int off = 1; off < 256; off <<= 1) {
        int v = (t >= off) ? part[t - off] : 0;
        __syncthreads();
        part[t] += v;
        __syncthreads();
    }
    int base = part[t] - s;
    for (int n = lo; n < hi; ++n) {
        int c = cnt[n];
        starts[n] = base; cursor[n] = base;
        cinv[n] = 1.0f / (float)(c > 0 ? c : 1);
        base += c;
    }
}

__global__ void fill_kernel(const int* __restrict__ ecol, int* __restrict__ cursor,
                            int* __restrict__ eidx) {
    int e = blockIdx.x * blockDim.x + threadIdx.x;
    if (e < NE) {
        int slot = atomicAdd(&cursor[ecol[e]], 1);
        eidx[slot] = e;
    }
}

// ---- aggregation: one wave per node, lane covers 2 cols; bf16 in, bf16 out ----
__global__ __launch_bounds__(256)
void agg_kernel(const unsigned short* __restrict__ eab, const int* __restrict__ starts,
                const int* __restrict__ cnt, const float* __restrict__ cinv,
                const int* __restrict__ eidx, unsigned short* __restrict__ aggb) {
    int n = blockIdx.x * 4 + (threadIdx.x >> 6);
    if (n >= NN) return;
    int lane = threadIdx.x & 63;
    int st = starts[n], de = cnt[n];
    float sx = 0.f, sy = 0.f;
    for (int i = 0; i < de; ++i) {
        int e = eidx[st + i];
        unsigned u = *(const unsigned*)&eab[(size_t)e * DD + lane * 2];
        sx += __uint_as_float(u << 16);
        sy += __uint_as_float(u & 0xffff0000u);
    }
    float ci = cinv[n];
    *(unsigned*)&aggb[(size_t)n * DD + lane * 2] = bc2(sx * ci, sy * ci);
}

// ---- fused MFMA MLP: 32 rows/block, 4 waves, NO gather phase ----
// stage1 A-frags loaded per-lane directly from bf16 shadows (x_bf / ea_bf / agg_bf);
// H' bf16 through LDS (nibble-swapped, b64 writes); 3 barriers total.
// Epilogue writes fp32 master += out AND bf16 shadow.
template <int K1, int ROWS_TOTAL, bool EDGE>
__global__ __launch_bounds__(256, 6)
void mlp_mfma(const unsigned short* __restrict__ xbf,
              const int* __restrict__ erow, const int* __restrict__ ecol,
              const unsigned short* __restrict__ auxbf,   // NODE: agg_bf ; EDGE: ea_bf
              float* __restrict__ target,                 // EDGE: ea fp32 ; NODE: x fp32
              unsigned short* __restrict__ shadow,        // EDGE: ea_bf ; NODE: x_bf
              const unsigned short* __restrict__ W1p, const unsigned short* __restrict__ W2p,
              const float* __restrict__ b1, const float* __restrict__ g1, const float* __restrict__ bt1,
              const float* __restrict__ b2, const float* __restrict__ g2, const float* __restrict__ bt2)
{
    constexpr int S1 = K1 / 32;
    constexpr int ROWS = 32;
    __shared__ unsigned short hsm[ROWS * 256];   // stage-1 activations, nibble-swapped cols
    __shared__ float red1[ROWS][8];
    __shared__ float red2[ROWS][4];

    const int tid  = threadIdx.x;
    const int lane = tid & 63;
    const int w    = tid >> 6;
    const int q    = lane >> 4;
    const int c15  = lane & 15;
    const int r0   = blockIdx.x * ROWS;

    // ---------------- per-lane A base pointers (row = mt*16 + c15) ----------------
    const unsigned short* aB0[2];
    const unsigned short* aB1[2];
    const unsigned short* aB2[2];
    #pragma unroll
    for (int mt = 0; mt < 2; ++mt) {
        int rm = r0 + (mt << 4) + c15;
        if (ROWS_TOTAL % ROWS != 0 && rm >= ROWS_TOTAL) rm = 0;  // clamped rows discarded later
        if (EDGE) {
            aB0[mt] = xbf + (size_t)erow[rm] * DD;
            aB1[mt] = xbf + (size_t)ecol[rm] * DD;
            aB2[mt] = auxbf + (size_t)rm * DD;
        } else {
            aB0[mt] = xbf + (size_t)rm * DD;
            aB1[mt] = auxbf + (size_t)rm * DD;
        }
    }

    // ---------------- stage 1 MFMA: wave w -> n-tiles 4w..4w+3, m-tiles 0..1 ----------------
    floatx4 acc[2][4];
    #pragma unroll
    for (int mt = 0; mt < 2; ++mt)
        #pragma unroll
        for (int ntl = 0; ntl < 4; ++ntl)
            acc[mt][ntl] = (floatx4){0.f, 0.f, 0.f, 0.f};

    #pragma unroll
    for (int s = 0; s < S1; ++s) {
        const int koff = (s << 5) + (q << 3);
        short8 af[2];
        #pragma unroll
        for (int mt = 0; mt < 2; ++mt) {
            const unsigned short* src;
            if (s < 4)      src = aB0[mt] + koff;
            else if (s < 8) src = aB1[mt] + (koff - 128);
            else            src = aB2[mt] + (koff - 256);
            af[mt] = *(const short8*)src;
        }
        #pragma unroll
        for (int ntl = 0; ntl < 4; ++ntl) {
            const short8 bf = *(const short8*)&W1p[((((((w << 2) + ntl) * S1) + s) << 6) + lane) << 3];
            #pragma unroll
            for (int mt = 0; mt < 2; ++mt)
                acc[mt][ntl] = __builtin_amdgcn_mfma_f32_16x16x32_bf16(af[mt], bf, acc[mt][ntl], 0, 0, 0);
        }
    }

    // bias + in-register LN1 partial stats
    float b1c[4], g1c[4], t1c[4];
    #pragma unroll
    for (int ntl = 0; ntl < 4; ++ntl) {
        int col = (((w << 2) + ntl) << 4) + c15;
        b1c[ntl] = b1[col]; g1c[ntl] = g1[col]; t1c[ntl] = bt1[col];
    }
    #pragma unroll
    for (int mt = 0; mt < 2; ++mt)
        #pragma unroll
        for (int r = 0; r < 4; ++r) {
            float p = 0.f, sq = 0.f;
            #pragma unroll
            for (int ntl = 0; ntl < 4; ++ntl) {
                float v = acc[mt][ntl][r] + b1c[ntl];
                acc[mt][ntl][r] = v;
                p += v; sq += v * v;
            }
            p += __shfl_xor(p, 1);  sq += __shfl_xor(sq, 1);
            p += __shfl_xor(p, 2);  sq += __shfl_xor(sq, 2);
            p += __shfl_xor(p, 4);  sq += __shfl_xor(sq, 4);
            p += __shfl_xor(p, 8);  sq += __shfl_xor(sq, 8);
            if (c15 == 0) {
                int row = (mt << 4) + (q << 2) + r;
                red1[row][(w << 1) + 0] = p;
                red1[row][(w << 1) + 1] = sq;
            }
        }
    __syncthreads();   // barrier 1: red1 visible

    // ---- apply LN1 + GELU in reg, write H' once as b64 (nibble-swapped cols) ----
    // orig col = (4w+ntl)*16 + c15  ->  col' = c15*16 + 4w + ntl (ntl contiguous)
    #pragma unroll
    for (int mt = 0; mt < 2; ++mt)
        #pragma unroll
        for (int r = 0; r < 4; ++r) {
            int row = (mt << 4) + (q << 2) + r;
            const float4 p0 = *(const float4*)&red1[row][0];
            const float4 p1 = *(const float4*)&red1[row][4];
            float p  = p0.x + p0.z + p1.x + p1.z;
            float sq = p0.y + p0.w + p1.y + p1.w;
            float mu = p * (1.0f / 256.0f);
            float rs = rsqrtf(sq * (1.0f / 256.0f) - mu * mu + LN_EPS);
            float y0 = gelu_fast((acc[mt][0][r] - mu) * rs * g1c[0] + t1c[0]);
            float y1 = gelu_fast((acc[mt][1][r] - mu) * rs * g1c[1] + t1c[1]);
            float y2 = gelu_fast((acc[mt][2][r] - mu) * rs * g1c[2] + t1c[2]);
            float y3 = gelu_fast((acc[mt][3][r] - mu) * rs * g1c[3] + t1c[3]);
            uint2 hp;
            hp.x = bc2(y0, y1);
            hp.y = bc2(y2, y3);
            int gg = (c15 << 1) + (w >> 1);
            int addr = row * 256 + (((gg ^ (row & 7)) << 3) | ((w & 1) << 2));
            *(uint2*)&hsm[addr] = hp;
        }
    __syncthreads();   // barrier 2: H' visible

    // ---------------- stage 2: wave w -> m-tile (w&1), n-tiles (w>>1)*4.. ----------------
    floatx4 acc2[4];
    #pragma unroll
    for (int j = 0; j < 4; ++j) acc2[j] = (floatx4){0.f, 0.f, 0.f, 0.f};

    const int mrow = ((w & 1) << 4) + c15;
    const int nh   = w >> 1;
    #pragma unroll
    for (int s = 0; s < 8; ++s) {
        int kgrp = ((s << 2) + q) ^ (mrow & 7);
        const short8 a = *(const short8*)&hsm[mrow * 256 + (kgrp << 3)];
        #pragma unroll
        for (int j = 0; j < 4; ++j) {
            int nt = (nh << 2) + j;
            const short8 b = *(const short8*)&W2p[((((nt << 3) + s) << 6) + lane) << 3];
            acc2[j] = __builtin_amdgcn_mfma_f32_16x16x32_bf16(a, b, acc2[j], 0, 0, 0);
        }
    }

    float b2c[4], g2c[4], t2c[4];
    #pragma unroll
    for (int j = 0; j < 4; ++j) {
        int col = (((nh << 2) + j) << 4) + c15;
        b2c[j] = b2[col]; g2c[j] = g2[col]; t2c[j] = bt2[col];
    }
    #pragma unroll
    for (int r = 0; r < 4; ++r) {
        float p = 0.f, sq = 0.f;
        #pragma unroll
        for (int j = 0; j < 4; ++j) {
            float v = acc2[j][r] + b2c[j];
            acc2[j][r] = v;
            p += v; sq += v * v;
        }
        p += __shfl_xor(p, 1);  sq += __shfl_xor(sq, 1);
        p += __shfl_xor(p, 2);  sq += __shfl_xor(sq, 2);
        p += __shfl_xor(p, 4);  sq += __shfl_xor(sq, 4);
        p += __shfl_xor(p, 8);  sq += __shfl_xor(sq, 8);
        if (c15 == 0) {
            int row = ((w & 1) << 4) + (q << 2) + r;
            red2[row][(nh << 1) + 0] = p;
            red2[row][(nh << 1) + 1] = sq;
        }
    }
    __syncthreads();   // barrier 3: red2 visible

    // ---------------- epilogue: LN2 + residual store (fp32 master + bf16 shadow) ----------------
    #pragma unroll
    for (int r = 0; r < 4; ++r) {
        int row = ((w & 1) << 4) + (q << 2) + r;
        const float4 pp = *(const float4*)&red2[row][0];
        float p  = pp.x + pp.z;
        float sq = pp.y + pp.w;
        float mu = p * (1.0f / 128.0f);
        float rs = rsqrtf(sq * (1.0f / 128.0f) - mu * mu + LN_EPS);
        int rowg = r0 + row;
        if (ROWS_TOTAL % ROWS == 0 || rowg < ROWS_TOTAL) {
            #pragma unroll
            for (int j = 0; j < 4; ++j) {
                int col = (((nh << 2) + j) << 4) + c15;
                float o = (acc2[j][r] - mu) * rs * g2c[j] + t2c[j];
                size_t off = (size_t)rowg * DD + col;
                float nv = target[off] + o;
                target[off] = nv;
                shadow[off] = f2bf(nv);
            }
        }
    }
}

extern "C" void kernel_launch(void* const* d_in, const int* in_sizes, int n_in,
                              void* d_out, int out_size, void* d_ws, size_t ws_size,
                              hipStream_t stream) {
    const float* x_in  = (const float*)d_in[0];
    const int*   ei    = (const int*)  d_in[1];
    const float* ea_in = (const float*)d_in[2];
    const float* ew1 = (const float*)d_in[3];
    const float* eb1 = (const float*)d_in[4];
    const float* eg1 = (const float*)d_in[5];
    const float* ebt1= (const float*)d_in[6];
    const float* ew2 = (const float*)d_in[7];
    const float* eb2 = (const float*)d_in[8];
    const float* eg2 = (const float*)d_in[9];
    const float* ebt2= (const float*)d_in[10];
    const float* nw1 = (const float*)d_in[11];
    const float* nb1 = (const float*)d_in[12];
    const float* ng1 = (const float*)d_in[13];
    const float* nbt1= (const float*)d_in[14];
    const float* nw2 = (const float*)d_in[15];
    const float* nb2 = (const float*)d_in[16];
    const float* ng2 = (const float*)d_in[17];
    const float* nbt2= (const float*)d_in[18];

    const int* erow = ei;
    const int* ecol = ei + NE;

    float* xbuf  = (float*)d_out;            // [NN, DD] fp32 master
    float* eabuf = (float*)d_out + NN * DD;  // [NE, DD] fp32 master

    // workspace layout (16B-aligned sections)
    unsigned short* ew1p = (unsigned short*)d_ws;
    unsigned short* ew2p = ew1p + N_EW1;
    unsigned short* nw1p = ew2p + N_EW2;
    unsigned short* nw2p = nw1p + N_NW1;
    unsigned short* x_bf  = nw2p + N_NW2;         // [NN*DD]
    unsigned short* ea_bf = x_bf + NN * DD;       // [NE*DD]
    unsigned short* agg_bf= ea_bf + NE * DD;      // [NN*DD]
    int*   cnt    = (int*)(agg_bf + NN * DD);
    int*   starts = cnt + NN;
    int*   cursor = starts + NN;
    int*   eidx   = cursor + NN;
    float* cinv   = (float*)(eidx + NE);

    hipMemcpyAsync(xbuf,  x_in,  (size_t)NN * DD * sizeof(float), hipMemcpyDeviceToDevice, stream);
    hipMemcpyAsync(eabuf, ea_in, (size_t)NE * DD * sizeof(float), hipMemcpyDeviceToDevice, stream);

    // bf16 shadows of initial state
    {
        int ntot = (NN * DD + NE * DD) / 4;
        cvt_shadow<<<(ntot + 255) / 256, 256, 0, stream>>>(x_in, ea_in, x_bf, ea_bf);
    }

    // CSR build
    hipMemsetAsync(cnt, 0, NN * sizeof(int), stream);
    hist_kernel<<<(NE + 255) / 256, 256, 0, stream>>>(ecol, cnt);
    scan_kernel<<<1, 256, 0, stream>>>(cnt, starts, cursor, cinv);
    fill_kernel<<<(NE + 255) / 256, 256, 0, stream>>>(ecol, cursor, eidx);

    // weight packing (stage-2 weights get the k-permutation)
    {
        int ntot = N_EW1 + N_EW2 + N_NW1 + N_NW2;
        pack_all<<<(ntot + 255) / 256, 256, 0, stream>>>(ew1, ew2, nw1, nw2, ew1p);
    }

    for (int i = 0; i < NL; ++i) {
        mlp_mfma<384, NE, true><<<NE / 32, 256, 0, stream>>>(
            x_bf, erow, ecol, ea_bf, eabuf, ea_bf,
            ew1p + (size_t)i * 384 * 256, ew2p + (size_t)i * 256 * 128,
            eb1 + (size_t)i * 256, eg1 + (size_t)i * 256, ebt1 + (size_t)i * 256,
            eb2 + (size_t)i * 128, eg2 + (size_t)i * 128, ebt2 + (size_t)i * 128);
        agg_kernel<<<(NN + 3) / 4, 256, 0, stream>>>(ea_bf, starts, cnt, cinv, eidx, agg_bf);
        mlp_mfma<256, NN, false><<<(NN + 31) / 32, 256, 0, stream>>>(
            x_bf, nullptr, nullptr, agg_bf, xbuf, x_bf,
            nw1p + (size_t)i * 256 * 256, nw2p + (size_t)i * 256 * 128,
            nb1 + (size_t)i * 256, ng1 + (size_t)i * 256, nbt1 + (size_t)i * 256,
            nb2 + (size_t)i * 128, ng2 + (size_t)i * 128, nbt2 + (size_t)i * 128);
    }
}